// Round 5
// baseline (485.163 us; speedup 1.0000x reference)
//
#include <hip/hip_runtime.h>
#include <cmath>

// Problem constants (B=4, H=12, S=2048, D=64, BLOCK=64, L=32, NUM_STEPS=4)
#define BH_ 48
#define NH_ 12
#define SS_ 2048

__device__ __forceinline__ float softplus_f(float x) {
    return fmaxf(x, 0.0f) + log1pf(expf(-fabsf(x)));
}

// ---------------------------------------------------------------------------
// Buffers (float32):
//   lp  : [BH][64(j)][32(l)][32(k)]      ws
//   rp  : [BH][32(k)][64(j)][64(i)]      ws
//   LQ  : [BH][64(j)][32(k)][64(v)]      ws
//   r2  : [BH][64(j)][32(k)]             ws   (also K-block means for kB<0>)
//   l2  : [BH][32(k)][64(j)]             ws
//   KR  : [BH][32(k)][64(j)][64(v)]      ALIASED ONTO d_out (also Y)
// KR<->out aliasing race-free: only kZ reads Y while writing out; block (bh,j)
// stages exactly the rows it later writes (same flat set), others disjoint.
// All compute kernels use 64-thread (single-wave) blocks: __syncthreads is
// barrier-free, normalize phases are row-per-thread (no shuffles), and matmuls
// use 8x8 / 4x4 / 4x8 register tiles with cyclic rows (row = grp + 8*a) so
// every LDS operand read is a conflict-free 8-lane broadcast.
// ---------------------------------------------------------------------------

__global__ __launch_bounds__(64) void kA0(const float* __restrict__ key,
                                          float* __restrict__ mean) {
    int blk = blockIdx.x; int bh = blk >> 5; int k = blk & 31;
    int t = threadIdx.x;
    const float* kb = key + ((size_t)bh * SS_ + k * 64) * 64;
    float acc = 0.f;
    #pragma unroll
    for (int i = 0; i < 64; ++i) acc += kb[i * 64 + t];
    mean[((size_t)bh * 32 + k) * 64 + t] = acc * (1.0f / 64.0f);
}

// kB: one block (1 wave) per (bh,j).
template <int STEP>
__global__ __launch_bounds__(64) void kB(const float* __restrict__ query,
                                         const float* __restrict__ attn_scale,
                                         const float* __restrict__ step_size,
                                         float* __restrict__ lp,
                                         const float* __restrict__ KR,  // mean at STEP==0
                                         const float* __restrict__ r2,
                                         float* __restrict__ LQ,
                                         float* __restrict__ l2) {
    int blk = blockIdx.x; int bh = blk >> 6; int j = blk & 63;
    int h = bh % NH_; int t = threadIdx.x;
    __shared__ float Qs[32][68];
    __shared__ float KRs[32][68];
    __shared__ float leS[32][36];
    __shared__ float t2S[32][36];

    float qscale = softplus_f(attn_scale[h]) * 0.125f;
    float sp0 = softplus_f(step_size[h * 8 + STEP]);

    for (int idx = t; idx < 512; idx += 64) {
        int r = idx >> 4, c4 = (idx & 15) * 4;
        float4 q = *(const float4*)&query[((size_t)bh * SS_ + r * 64 + j) * 64 + c4];
        q.x *= qscale; q.y *= qscale; q.z *= qscale; q.w *= qscale;
        *(float4*)&Qs[r][c4] = q;
        float4 kr;
        if (STEP == 0) kr = *(const float4*)&KR[((size_t)bh * 32 + r) * 64 + c4];
        else           kr = *(const float4*)&KR[((size_t)(bh * 32 + r) * 64 + j) * 64 + c4];
        *(float4*)&KRs[r][c4] = kr;
    }

    // owner mapping: row lo = t>>1 (l), 16 cols c0..c0+15 (k)
    int lo = t >> 1, c0 = (t & 1) * 16;
    float* lpj = lp + ((size_t)(bh * 64 + j)) * 1024;
    float lpv[16], r2v[16];
    if (STEP == 0) {
        #pragma unroll
        for (int d = 0; d < 16; ++d) { lpv[d] = 0.17677669529663687f; r2v[d] = 1.0f / 64.0f; }
    } else {
        #pragma unroll
        for (int q4 = 0; q4 < 4; ++q4) {
            float4 v = *(const float4*)&lpj[lo * 32 + c0 + q4 * 4];
            lpv[q4*4] = v.x; lpv[q4*4+1] = v.y; lpv[q4*4+2] = v.z; lpv[q4*4+3] = v.w;
            float4 w = *(const float4*)&r2[((size_t)(bh * 64 + j)) * 32 + c0 + q4 * 4];
            r2v[q4*4] = w.x; r2v[q4*4+1] = w.y; r2v[q4*4+2] = w.z; r2v[q4*4+3] = w.w;
        }
    }
    float s = 0.f;
    #pragma unroll
    for (int d = 0; d < 16; ++d) s += lpv[d] * lpv[d];
    s += __shfl_xor(s, 1);
    float n = sqrtf(s);
    float invn = (n > 0.f) ? 1.0f / n : 0.f;
    float ls[16], le[16];
    #pragma unroll
    for (int d = 0; d < 16; ++d) { ls[d] = lpv[d] * invn; le[d] = ls[d] * ls[d]; }
    #pragma unroll
    for (int q4 = 0; q4 < 4; ++q4)
        *(float4*)&leS[lo][c0 + q4 * 4] = make_float4(le[q4*4], le[q4*4+1], le[q4*4+2], le[q4*4+3]);
    __syncthreads();

    // t2l[l][k] = sum_v Qs[l][v]*KRs[k][v]; rows (t>>3)+8a, cols (t&7)+8b (4x4)
    {
        int rg = t >> 3, cg = t & 7;
        float acc[4][4] = {};
        #pragma unroll 2
        for (int v4 = 0; v4 < 16; ++v4) {
            float4 qv[4], rv4[4];
            #pragma unroll
            for (int d = 0; d < 4; ++d) qv[d]  = *(const float4*)&Qs[rg + 8*d][v4*4];
            #pragma unroll
            for (int d = 0; d < 4; ++d) rv4[d] = *(const float4*)&KRs[cg + 8*d][v4*4];
            #pragma unroll
            for (int a = 0; a < 4; ++a)
                #pragma unroll
                for (int b = 0; b < 4; ++b)
                    acc[a][b] += qv[a].x*rv4[b].x + qv[a].y*rv4[b].y +
                                 qv[a].z*rv4[b].z + qv[a].w*rv4[b].w;
        }
        #pragma unroll
        for (int a = 0; a < 4; ++a)
            #pragma unroll
            for (int b = 0; b < 4; ++b) t2S[rg + 8*a][cg + 8*b] = acc[a][b];
    }
    __syncthreads();

    // owner: dl, project, update lp
    {
        float dl[16]; float rd = 0.f;
        #pragma unroll
        for (int q4 = 0; q4 < 4; ++q4) {
            float4 t2 = *(const float4*)&t2S[lo][c0 + q4 * 4];
            float tv[4] = {t2.x, t2.y, t2.z, t2.w};
            #pragma unroll
            for (int d = 0; d < 4; ++d) {
                int i = q4*4 + d;
                dl[i] = 2.f * ls[i] * (r2v[i] * le[i] - tv[d]);
                rd += ls[i] * dl[i];
            }
        }
        rd += __shfl_xor(rd, 1);
        #pragma unroll
        for (int q4 = 0; q4 < 4; ++q4) {
            float o0 = lpv[q4*4]   - sp0 * ((dl[q4*4]   - ls[q4*4]   * rd) * invn);
            float o1 = lpv[q4*4+1] - sp0 * ((dl[q4*4+1] - ls[q4*4+1] * rd) * invn);
            float o2 = lpv[q4*4+2] - sp0 * ((dl[q4*4+2] - ls[q4*4+2] * rd) * invn);
            float o3 = lpv[q4*4+3] - sp0 * ((dl[q4*4+3] - ls[q4*4+3] * rd) * invn);
            *(float4*)&lpj[lo * 32 + c0 + q4 * 4] = make_float4(o0, o1, o2, o3);
        }
    }

    // LQ[k][v] = sum_l le[l][k]*Qs[l][v] (old left); rows (t>>3)+8a, cols (t&7)*4 & +32
    {
        int rg = t >> 3, v0 = (t & 7) * 4;
        float4 b0[4] = {{0,0,0,0},{0,0,0,0},{0,0,0,0},{0,0,0,0}};
        float4 b1[4] = {{0,0,0,0},{0,0,0,0},{0,0,0,0},{0,0,0,0}};
        #pragma unroll 2
        for (int l4 = 0; l4 < 8; ++l4) {
            #pragma unroll
            for (int dl = 0; dl < 4; ++dl) {
                int l = l4 * 4 + dl;
                float4 q0 = *(const float4*)&Qs[l][v0];
                float4 q1 = *(const float4*)&Qs[l][v0 + 32];
                #pragma unroll
                for (int a = 0; a < 4; ++a) {
                    float e = leS[l][rg + 8*a];
                    b0[a].x += e*q0.x; b0[a].y += e*q0.y; b0[a].z += e*q0.z; b0[a].w += e*q0.w;
                    b1[a].x += e*q1.x; b1[a].y += e*q1.y; b1[a].z += e*q1.z; b1[a].w += e*q1.w;
                }
            }
        }
        float* LQj = LQ + ((size_t)(bh * 64 + j)) * 2048;
        #pragma unroll
        for (int a = 0; a < 4; ++a) {
            *(float4*)&LQj[(rg + 8*a) * 64 + v0] = b0[a];
            *(float4*)&LQj[(rg + 8*a) * 64 + v0 + 32] = b1[a];
        }
    }

    // l2[k] = sum_l le[l][k]^2
    if (t < 32) {
        float s2 = 0.f;
        #pragma unroll
        for (int l = 0; l < 32; ++l) { float x = leS[l][t]; s2 += x * x; }
        l2[(bh * 32 + t) * 64 + j] = s2;
    }
}

// kCA: one block (1 wave) per (bh,k).  Owner phase: thread t owns full row j=t.
template <int STEP>
__global__ __launch_bounds__(64) void kCA(const float* __restrict__ key,
                                          const float* __restrict__ value,
                                          const float* __restrict__ step_size,
                                          float* __restrict__ rp,
                                          const float* __restrict__ LQ,
                                          const float* __restrict__ l2,
                                          float* __restrict__ KR,
                                          float* __restrict__ r2) {
    int blk = blockIdx.x; int bh = blk >> 5; int k = blk & 31;
    int h = bh % NH_; int t = threadIdx.x;
    __shared__ float kS[64][68];
    __shared__ float lqS[64][68];   // LQ -> t2r -> dr -> right'
    __shared__ float l2S[64];

    float sp1 = softplus_f(step_size[h * 8 + 4 + STEP]);
    float* rpk = rp + ((size_t)(bh * 32 + k)) * 4096;

    for (int idx = t; idx < 1024; idx += 64) {
        int r = idx >> 4, c4 = (idx & 15) * 4;
        *(float4*)&kS[r][c4]  = *(const float4*)&key[((size_t)bh * SS_ + k * 64 + r) * 64 + c4];
        *(float4*)&lqS[r][c4] = *(const float4*)&LQ[((size_t)(bh * 64 + r) * 32 + k) * 64 + c4];
    }
    l2S[t] = l2[(bh * 32 + k) * 64 + t];
    __syncthreads();

    int tj = t >> 3, ti = t & 7;
    // t2r[j][i] = sum_v lqS[j][v]*kS[i][v]; rows tj+8a, cols ti+8b (8x8 tile)
    {
        float acc[8][8] = {};
        #pragma unroll 2
        for (int v4 = 0; v4 < 16; ++v4) {
            float4 lq[8], kk[8];
            #pragma unroll
            for (int d = 0; d < 8; ++d) lq[d] = *(const float4*)&lqS[tj + 8*d][v4*4];
            #pragma unroll
            for (int d = 0; d < 8; ++d) kk[d] = *(const float4*)&kS[ti + 8*d][v4*4];
            #pragma unroll
            for (int a = 0; a < 8; ++a)
                #pragma unroll
                for (int b = 0; b < 8; ++b)
                    acc[a][b] += lq[a].x*kk[b].x + lq[a].y*kk[b].y +
                                 lq[a].z*kk[b].z + lq[a].w*kk[b].w;
        }
        __syncthreads();   // all t2r reads of lqS done; reuse lqS for t2r values
        #pragma unroll
        for (int a = 0; a < 8; ++a)
            #pragma unroll
            for (int b = 0; b < 8; ++b) lqS[tj + 8*a][ti + 8*b] = acc[a][b];
    }
    if (STEP == 3) {   // stage X over kS (kS t2r reads completed at sync above)
        for (int idx = t; idx < 1024; idx += 64) {
            int r = idx >> 4, c4 = (idx & 15) * 4;
            *(float4*)&kS[r][c4] = *(const float4*)&value[((size_t)bh * SS_ + k * 64 + r) * 64 + c4];
        }
    }
    __syncthreads();

    // owner: thread t owns row j=t (all 64 i).
    float rv[64];
    if (STEP == 0) {
        #pragma unroll
        for (int i = 0; i < 64; ++i) rv[i] = 0.125f;
    } else {
        #pragma unroll
        for (int q4 = 0; q4 < 16; ++q4) {
            float4 v = *(const float4*)&rpk[t * 64 + q4 * 4];
            rv[q4*4] = v.x; rv[q4*4+1] = v.y; rv[q4*4+2] = v.z; rv[q4*4+3] = v.w;
        }
    }
    float s2 = 0.f;
    #pragma unroll
    for (int i = 0; i < 64; ++i) s2 += rv[i] * rv[i];
    float n = sqrtf(s2);
    float invn = (n > 0.f) ? 1.0f / n : 0.f;
    float l2j = l2S[t];
    // pass 1: dr1 into lqS row t (in place over t2r), accumulate dot
    float dot = 0.f;
    #pragma unroll
    for (int q4 = 0; q4 < 16; ++q4) {
        float4 tv = *(const float4*)&lqS[t][q4 * 4];
        float rs0 = rv[q4*4]   * invn; float d0 = 2.f*rs0*(l2j*rs0*rs0 - tv.x); dot += rs0*d0;
        float rs1 = rv[q4*4+1] * invn; float d1 = 2.f*rs1*(l2j*rs1*rs1 - tv.y); dot += rs1*d1;
        float rs2 = rv[q4*4+2] * invn; float d2 = 2.f*rs2*(l2j*rs2*rs2 - tv.z); dot += rs2*d2;
        float rs3 = rv[q4*4+3] * invn; float d3 = 2.f*rs3*(l2j*rs3*rs3 - tv.w); dot += rs3*d3;
        *(float4*)&lqS[t][q4 * 4] = make_float4(d0, d1, d2, d3);
    }
    // pass 2: project, update rv, new norms
    float s2n = 0.f, s4n = 0.f;
    #pragma unroll
    for (int q4 = 0; q4 < 16; ++q4) {
        float4 dv4 = *(const float4*)&lqS[t][q4 * 4];
        float dvv[4] = {dv4.x, dv4.y, dv4.z, dv4.w};
        #pragma unroll
        for (int d = 0; d < 4; ++d) {
            int i = q4*4 + d;
            float rs = rv[i] * invn;
            float dd = (dvv[d] - rs * dot) * invn;
            rv[i] -= sp1 * dd;
            float x2 = rv[i] * rv[i];
            s2n += x2; s4n += x2 * x2;
        }
    }
    float nn = sqrtf(s2n);
    float inn = (nn > 0.f) ? 1.0f / nn : 0.f;
    if (STEP < 3) {
        #pragma unroll
        for (int q4 = 0; q4 < 16; ++q4)
            *(float4*)&rpk[t * 64 + q4 * 4] =
                make_float4(rv[q4*4], rv[q4*4+1], rv[q4*4+2], rv[q4*4+3]);
        float i2 = inn * inn;
        r2[(bh * 64 + t) * 32 + k] = i2 * i2 * s4n;
    }
    // right' into lqS row t
    #pragma unroll
    for (int q4 = 0; q4 < 16; ++q4) {
        float a0 = rv[q4*4]*inn, a1 = rv[q4*4+1]*inn, a2 = rv[q4*4+2]*inn, a3 = rv[q4*4+3]*inn;
        *(float4*)&lqS[t][q4 * 4] = make_float4(a0*a0, a1*a1, a2*a2, a3*a3);
    }
    __syncthreads();

    // KR[j][v] = sum_i right'[j][i]*kS[i][v]  (Y at STEP==3); rows tj+8a, cols ti*4 & ti*4+32
    {
        float4 oc0[8] = {{0,0,0,0},{0,0,0,0},{0,0,0,0},{0,0,0,0},
                         {0,0,0,0},{0,0,0,0},{0,0,0,0},{0,0,0,0}};
        float4 oc1[8] = {{0,0,0,0},{0,0,0,0},{0,0,0,0},{0,0,0,0},
                         {0,0,0,0},{0,0,0,0},{0,0,0,0},{0,0,0,0}};
        int v0 = ti * 4;
        #pragma unroll 2
        for (int i4 = 0; i4 < 16; ++i4) {
            float4 rg[8];
            #pragma unroll
            for (int d = 0; d < 8; ++d) rg[d] = *(const float4*)&lqS[tj + 8*d][i4*4];
            #pragma unroll
            for (int di = 0; di < 4; ++di) {
                float4 ka = *(const float4*)&kS[i4*4 + di][v0];
                float4 kb = *(const float4*)&kS[i4*4 + di][v0 + 32];
                #pragma unroll
                for (int a = 0; a < 8; ++a) {
                    float r = (di == 0) ? rg[a].x : (di == 1) ? rg[a].y :
                              (di == 2) ? rg[a].z : rg[a].w;
                    oc0[a].x += r*ka.x; oc0[a].y += r*ka.y; oc0[a].z += r*ka.z; oc0[a].w += r*ka.w;
                    oc1[a].x += r*kb.x; oc1[a].y += r*kb.y; oc1[a].z += r*kb.z; oc1[a].w += r*kb.w;
                }
            }
        }
        float* KRk = KR + ((size_t)(bh * 32 + k)) * 4096;
        #pragma unroll
        for (int a = 0; a < 8; ++a) {
            *(float4*)&KRk[(tj + 8*a) * 64 + v0] = oc0[a];
            *(float4*)&KRk[(tj + 8*a) * 64 + v0 + 32] = oc1[a];
        }
    }
}

// kZ: one block (1 wave) per (bh,j).  Z[l][v] = sum_k left[l][k]*Y[k][v].
__global__ __launch_bounds__(64) void kZ(const float* __restrict__ lp,
                                         const float* Y,
                                         float* out) {
    int blk = blockIdx.x; int bh = blk >> 6; int j = blk & 63;
    int t = threadIdx.x;
    __shared__ float Ys[32][68];
    __shared__ float leS[32][36];

    for (int idx = t; idx < 512; idx += 64) {
        int r = idx >> 4, c4 = (idx & 15) * 4;
        *(float4*)&Ys[r][c4] = *(const float4*)&Y[((size_t)(bh * 32 + r) * 64 + j) * 64 + c4];
    }
    int lo = t >> 1, c0 = (t & 1) * 16;
    const float* lpj = lp + ((size_t)(bh * 64 + j)) * 1024;
    float lpv[16];
    #pragma unroll
    for (int q4 = 0; q4 < 4; ++q4) {
        float4 v = *(const float4*)&lpj[lo * 32 + c0 + q4 * 4];
        lpv[q4*4] = v.x; lpv[q4*4+1] = v.y; lpv[q4*4+2] = v.z; lpv[q4*4+3] = v.w;
    }
    float s = 0.f;
    #pragma unroll
    for (int d = 0; d < 16; ++d) s += lpv[d] * lpv[d];
    s += __shfl_xor(s, 1);
    float n = sqrtf(s);
    float invn = (n > 0.f) ? 1.0f / n : 0.f;
    #pragma unroll
    for (int q4 = 0; q4 < 4; ++q4) {
        float a0 = lpv[q4*4]*invn, a1 = lpv[q4*4+1]*invn, a2 = lpv[q4*4+2]*invn, a3 = lpv[q4*4+3]*invn;
        *(float4*)&leS[lo][c0 + q4 * 4] = make_float4(a0*a0, a1*a1, a2*a2, a3*a3);
    }
    __syncthreads();

    {
        int rg = t >> 3, v0 = (t & 7) * 4;
        float4 b0[4] = {{0,0,0,0},{0,0,0,0},{0,0,0,0},{0,0,0,0}};
        float4 b1[4] = {{0,0,0,0},{0,0,0,0},{0,0,0,0},{0,0,0,0}};
        #pragma unroll 2
        for (int k4 = 0; k4 < 8; ++k4) {
            #pragma unroll
            for (int dk = 0; dk < 4; ++dk) {
                int kk = k4 * 4 + dk;
                float4 y0 = *(const float4*)&Ys[kk][v0];
                float4 y1 = *(const float4*)&Ys[kk][v0 + 32];
                #pragma unroll
                for (int a = 0; a < 4; ++a) {
                    float e = leS[rg + 8*a][kk];
                    b0[a].x += e*y0.x; b0[a].y += e*y0.y; b0[a].z += e*y0.z; b0[a].w += e*y0.w;
                    b1[a].x += e*y1.x; b1[a].y += e*y1.y; b1[a].z += e*y1.z; b1[a].w += e*y1.w;
                }
            }
        }
        #pragma unroll
        for (int a = 0; a < 4; ++a) {
            *(float4*)&out[((size_t)bh * SS_ + (rg + 8*a) * 64 + j) * 64 + v0] = b0[a];
            *(float4*)&out[((size_t)bh * SS_ + (rg + 8*a) * 64 + j) * 64 + v0 + 32] = b1[a];
        }
    }
}

extern "C" void kernel_launch(void* const* d_in, const int* in_sizes, int n_in,
                              void* d_out, int out_size, void* d_ws, size_t ws_size,
                              hipStream_t stream) {
    const float* query = (const float*)d_in[0];
    const float* key   = (const float*)d_in[1];
    const float* value = (const float*)d_in[2];
    const float* attn  = (const float*)d_in[3];
    const float* ss    = (const float*)d_in[4];
    float* out = (float*)d_out;

    const size_t n_lp = (size_t)BH_ * 64 * 32 * 32;
    const size_t n_rp = (size_t)BH_ * 32 * 64 * 64;
    const size_t n_LQ = (size_t)BH_ * 64 * 32 * 64;
    const size_t n_r2 = (size_t)BH_ * 64 * 32;
    const size_t n_l2 = (size_t)BH_ * 32 * 64;
    const size_t need = (n_lp + n_rp + n_LQ + n_r2 + n_l2) * sizeof(float); // ~63.7 MB
    if (ws_size < need) return;

    float* ws = (float*)d_ws;
    float* lp = ws;
    float* rp = lp + n_lp;
    float* LQ = rp + n_rp;
    float* r2 = LQ + n_LQ;
    float* l2 = r2 + n_r2;
    float* KR = out;       // KR / Y aliased onto d_out
    float* mean = r2;      // K-block means live in r2 until kCA<0> writes real r2

    dim3 blkD(64);
    const int gK = BH_ * 32;   // 1536
    const int gJ = BH_ * 64;   // 3072

    kA0<<<gK, blkD, 0, stream>>>(key, mean);
    kB<0><<<gJ, blkD, 0, stream>>>(query, attn, ss, lp, mean, r2, LQ, l2);
    kCA<0><<<gK, blkD, 0, stream>>>(key, value, ss, rp, LQ, l2, KR, r2);
    kB<1><<<gJ, blkD, 0, stream>>>(query, attn, ss, lp, KR, r2, LQ, l2);
    kCA<1><<<gK, blkD, 0, stream>>>(key, value, ss, rp, LQ, l2, KR, r2);
    kB<2><<<gJ, blkD, 0, stream>>>(query, attn, ss, lp, KR, r2, LQ, l2);
    kCA<2><<<gK, blkD, 0, stream>>>(key, value, ss, rp, LQ, l2, KR, r2);
    kB<3><<<gJ, blkD, 0, stream>>>(query, attn, ss, lp, KR, r2, LQ, l2);
    kCA<3><<<gK, blkD, 0, stream>>>(key, value, ss, rp, LQ, l2, KR, r2);  // emits Y
    kZ<<<gJ, blkD, 0, stream>>>(lp, KR, out);
}

// Round 6
// 332.880 us; speedup vs baseline: 1.4575x; 1.4575x over previous
//
#include <hip/hip_runtime.h>
#include <cmath>

// Problem constants (B=4, H=12, S=2048, D=64, BLOCK=64, L=32, NUM_STEPS=4)
#define BH_ 48
#define NH_ 12
#define SS_ 2048

typedef __attribute__((ext_vector_type(8))) short s8v;   // 8 bf16 = 4 VGPR (MFMA A/B frag)
typedef __attribute__((ext_vector_type(4))) float f4v;   // MFMA C/D frag
typedef unsigned short u16;
typedef unsigned int u32;

__device__ __forceinline__ float softplus_f(float x) {
    return fmaxf(x, 0.0f) + log1pf(expf(-fabsf(x)));
}

// 3-way bf16 split: x ~= h + m + l with |l| ~ 2^-16|x|; kept products h*h'+h*m'+m*h'+h*l'+l*h'+m*m'
// give ~2^-24 relative error (fp32-equivalent) on the GD-loop matmuls.
__device__ __forceinline__ void split3(float x, u16& h, u16& m, u16& l) {
    u32 u = __float_as_uint(x);
    h = (u16)(u >> 16);
    float r1 = x - __uint_as_float(u & 0xFFFF0000u);
    u32 u1 = __float_as_uint(r1);
    m = (u16)(u1 >> 16);
    float r2 = r1 - __uint_as_float(u1 & 0xFFFF0000u);
    l = (u16)(__float_as_uint(r2) >> 16);
}

__device__ __forceinline__ f4v mm6(s8v ah, s8v am, s8v al, s8v bh, s8v bm, s8v bl, f4v acc) {
    acc = __builtin_amdgcn_mfma_f32_16x16x32_bf16(ah, bh, acc, 0, 0, 0);
    acc = __builtin_amdgcn_mfma_f32_16x16x32_bf16(ah, bm, acc, 0, 0, 0);
    acc = __builtin_amdgcn_mfma_f32_16x16x32_bf16(am, bh, acc, 0, 0, 0);
    acc = __builtin_amdgcn_mfma_f32_16x16x32_bf16(ah, bl, acc, 0, 0, 0);
    acc = __builtin_amdgcn_mfma_f32_16x16x32_bf16(al, bh, acc, 0, 0, 0);
    acc = __builtin_amdgcn_mfma_f32_16x16x32_bf16(am, bm, acc, 0, 0, 0);
    return acc;
}

__device__ __forceinline__ float fget(const float4& v, int q) {
    return (q == 0) ? v.x : (q == 1) ? v.y : (q == 2) ? v.z : v.w;
}

// ---------------------------------------------------------------------------
// Buffers (float32):
//   lp  : [BH][64(j)][32(l)][32(k)]      ws
//   rp  : [BH][32(k)][64(j)][64(i)]      ws
//   LQ  : [BH][64(j)][32(k)][64(v)]      ws
//   r2  : [BH][64(j)][32(k)]             ws   (also K-block means for kB<0>)
//   l2  : [BH][32(k)][64(j)]             ws
//   KR  : [BH][32(k)][64(j)][64(v)]      ALIASED ONTO d_out (also Y)
// ---------------------------------------------------------------------------

__global__ __launch_bounds__(64) void kA0(const float* __restrict__ key,
                                          float* __restrict__ mean) {
    int blk = blockIdx.x; int bh = blk >> 5; int k = blk & 31;
    int t = threadIdx.x;
    const float* kb = key + ((size_t)bh * SS_ + k * 64) * 64;
    float acc = 0.f;
    #pragma unroll
    for (int i = 0; i < 64; ++i) acc += kb[i * 64 + t];
    mean[((size_t)bh * 32 + k) * 64 + t] = acc * (1.0f / 64.0f);
}

// kB: one block (4 waves) per (bh,j).  t2l and LQ on MFMA (bf16 x6).
template <int STEP>
__global__ __launch_bounds__(256) void kB(const float* __restrict__ query,
                                          const float* __restrict__ attn_scale,
                                          const float* __restrict__ step_size,
                                          float* __restrict__ lp,
                                          const float* __restrict__ KR,  // mean at STEP==0
                                          const float* __restrict__ r2,
                                          float* __restrict__ LQ,
                                          float* __restrict__ l2) {
    int blk = blockIdx.x; int bh = blk >> 6; int j = blk & 63;
    int h = bh % NH_; int t = threadIdx.x;
    __shared__ __align__(16) short Qh[32][72], Qm[32][72], Ql[32][72];     // Q planes [l][v]
    __shared__ __align__(16) short QTh[64][40], QTm[64][40], QTl[64][40];  // Q^T planes [v][l]
    __shared__ __align__(16) short Rh[32][72], Rm[32][72], Rl[32][72];     // KR planes [k][v]
    __shared__ __align__(16) short Th[32][40], Tm[32][40], Tl[32][40];     // le^T planes [k][l]
    __shared__ float leS[32][33];
    __shared__ float t2S[32][36];

    float qscale = softplus_f(attn_scale[h]) * 0.125f;
    float sp0 = softplus_f(step_size[h * 8 + STEP]);

    // ---- staging ----
    if (t < 128) {
        // Q: 4x4 blocks; write normal planes + transposed planes
        int l0 = 4 * (t >> 4), v0 = 4 * (t & 15);
        float4 x[4];
        #pragma unroll
        for (int r = 0; r < 4; ++r) {
            x[r] = *(const float4*)&query[((size_t)bh * SS_ + (l0 + r) * 64 + j) * 64 + v0];
            x[r].x *= qscale; x[r].y *= qscale; x[r].z *= qscale; x[r].w *= qscale;
        }
        u16 hh[4][4], mm[4][4], ll[4][4];   // [r][q]
        #pragma unroll
        for (int r = 0; r < 4; ++r) {
            split3(x[r].x, hh[r][0], mm[r][0], ll[r][0]);
            split3(x[r].y, hh[r][1], mm[r][1], ll[r][1]);
            split3(x[r].z, hh[r][2], mm[r][2], ll[r][2]);
            split3(x[r].w, hh[r][3], mm[r][3], ll[r][3]);
        }
        #pragma unroll
        for (int r = 0; r < 4; ++r) {
            *(short4*)&Qh[l0 + r][v0] = make_short4(hh[r][0], hh[r][1], hh[r][2], hh[r][3]);
            *(short4*)&Qm[l0 + r][v0] = make_short4(mm[r][0], mm[r][1], mm[r][2], mm[r][3]);
            *(short4*)&Ql[l0 + r][v0] = make_short4(ll[r][0], ll[r][1], ll[r][2], ll[r][3]);
        }
        #pragma unroll
        for (int q = 0; q < 4; ++q) {
            *(short4*)&QTh[v0 + q][l0] = make_short4(hh[0][q], hh[1][q], hh[2][q], hh[3][q]);
            *(short4*)&QTm[v0 + q][l0] = make_short4(mm[0][q], mm[1][q], mm[2][q], mm[3][q]);
            *(short4*)&QTl[v0 + q][l0] = make_short4(ll[0][q], ll[1][q], ll[2][q], ll[3][q]);
        }
    } else {
        int tt = t & 127;
        #pragma unroll
        for (int it = 0; it < 4; ++it) {
            int idx = tt + 128 * it;
            int r = idx >> 4, c4 = (idx & 15) * 4;
            float4 x;
            if (STEP == 0) x = *(const float4*)&KR[((size_t)bh * 32 + r) * 64 + c4];
            else           x = *(const float4*)&KR[((size_t)(bh * 32 + r) * 64 + j) * 64 + c4];
            u16 h0, m0_, l0_, h1, m1, l1, h2, m2, l2_, h3, m3, l3;
            split3(x.x, h0, m0_, l0_); split3(x.y, h1, m1, l1);
            split3(x.z, h2, m2, l2_); split3(x.w, h3, m3, l3);
            *(short4*)&Rh[r][c4] = make_short4(h0, h1, h2, h3);
            *(short4*)&Rm[r][c4] = make_short4(m0_, m1, m2, m3);
            *(short4*)&Rl[r][c4] = make_short4(l0_, l1, l2_, l3);
        }
    }

    // ---- owner normalize (row lo, 8 lanes x 4 cols) ----
    int lo = t >> 3, c0 = (t & 7) * 4;
    float* lpj = lp + ((size_t)(bh * 64 + j)) * 1024;
    float lpv[4], r2v[4];
    if (STEP == 0) {
        #pragma unroll
        for (int d = 0; d < 4; ++d) { lpv[d] = 0.17677669529663687f; r2v[d] = 1.0f / 64.0f; }
    } else {
        float4 v = *(const float4*)&lpj[lo * 32 + c0];
        lpv[0] = v.x; lpv[1] = v.y; lpv[2] = v.z; lpv[3] = v.w;
        float4 w = *(const float4*)&r2[((size_t)(bh * 64 + j)) * 32 + c0];
        r2v[0] = w.x; r2v[1] = w.y; r2v[2] = w.z; r2v[3] = w.w;
    }
    float s = lpv[0]*lpv[0] + lpv[1]*lpv[1] + lpv[2]*lpv[2] + lpv[3]*lpv[3];
    s += __shfl_xor(s, 1); s += __shfl_xor(s, 2); s += __shfl_xor(s, 4);
    float n = sqrtf(s);
    float invn = (n > 0.f) ? 1.0f / n : 0.f;
    float ls[4], le[4];
    #pragma unroll
    for (int d = 0; d < 4; ++d) {
        ls[d] = lpv[d] * invn; le[d] = ls[d] * ls[d];
        leS[lo][c0 + d] = le[d];
        u16 eh, em, el;
        split3(le[d], eh, em, el);
        Th[c0 + d][lo] = (short)eh; Tm[c0 + d][lo] = (short)em; Tl[c0 + d][lo] = (short)el;
    }
    __syncthreads();   // sync1

    int w = t >> 6, lane = t & 63;
    int fr = lane & 15, fk = (lane >> 4) * 8;

    // ---- t2l[l][k] = Q . KR^T   (C 32x32, 4 tiles, 1 per wave) ----
    {
        int m0 = (w >> 1) * 16, n0 = (w & 1) * 16;
        f4v acc = {0, 0, 0, 0};
        #pragma unroll
        for (int k0 = 0; k0 < 64; k0 += 32) {
            s8v ah = *(const s8v*)&Qh[m0 + fr][k0 + fk];
            s8v am = *(const s8v*)&Qm[m0 + fr][k0 + fk];
            s8v al = *(const s8v*)&Ql[m0 + fr][k0 + fk];
            s8v bh_ = *(const s8v*)&Rh[n0 + fr][k0 + fk];
            s8v bm_ = *(const s8v*)&Rm[n0 + fr][k0 + fk];
            s8v bl_ = *(const s8v*)&Rl[n0 + fr][k0 + fk];
            acc = mm6(ah, am, al, bh_, bm_, bl_, acc);
        }
        #pragma unroll
        for (int g = 0; g < 4; ++g) t2S[m0 + (lane >> 4) * 4 + g][n0 + fr] = acc[g];
    }

    // ---- LQ[k][v] = le^T . Q^T-style TN   (C 32x64, 8 tiles, 2 per wave) ----
    {
        int m0 = (w & 1) * 16, nb = (w >> 1) * 32;
        s8v ah = *(const s8v*)&Th[m0 + fr][fk];
        s8v am = *(const s8v*)&Tm[m0 + fr][fk];
        s8v al = *(const s8v*)&Tl[m0 + fr][fk];
        float* LQj = LQ + ((size_t)(bh * 64 + j)) * 2048;
        #pragma unroll
        for (int half = 0; half < 2; ++half) {
            int n0 = nb + half * 16;
            s8v bh_ = *(const s8v*)&QTh[n0 + fr][fk];
            s8v bm_ = *(const s8v*)&QTm[n0 + fr][fk];
            s8v bl_ = *(const s8v*)&QTl[n0 + fr][fk];
            f4v acc = {0, 0, 0, 0};
            acc = mm6(ah, am, al, bh_, bm_, bl_, acc);
            #pragma unroll
            for (int g = 0; g < 4; ++g)
                LQj[(m0 + (lane >> 4) * 4 + g) * 64 + n0 + fr] = acc[g];
        }
    }

    // ---- l2[k] = sum_l le[l][k]^2 ----
    if (t < 32) {
        float s2 = 0.f;
        #pragma unroll
        for (int l = 0; l < 32; ++l) { float x = leS[l][t]; s2 += x * x; }
        l2[(bh * 32 + t) * 64 + j] = s2;
    }
    __syncthreads();   // sync2

    // ---- dl owner: project + update lp ----
    {
        float dl[4]; float rd = 0.f;
        #pragma unroll
        for (int d = 0; d < 4; ++d) {
            float t2 = t2S[lo][c0 + d];
            dl[d] = 2.f * ls[d] * (r2v[d] * le[d] - t2);
            rd += ls[d] * dl[d];
        }
        rd += __shfl_xor(rd, 1); rd += __shfl_xor(rd, 2); rd += __shfl_xor(rd, 4);
        float4 outv;
        outv.x = lpv[0] - sp0 * ((dl[0] - ls[0] * rd) * invn);
        outv.y = lpv[1] - sp0 * ((dl[1] - ls[1] * rd) * invn);
        outv.z = lpv[2] - sp0 * ((dl[2] - ls[2] * rd) * invn);
        outv.w = lpv[3] - sp0 * ((dl[3] - ls[3] * rd) * invn);
        *(float4*)&lpj[lo * 32 + c0] = outv;
    }
}

// kCA: one block (4 waves) per (bh,k).  t2r and KR on MFMA (bf16 x6).
// LDS pool (55296 B): A planes (lq -> t2S alias -> right' planes),
//                     B planes (K -> K^T/X^T planes).
template <int STEP>
__global__ __launch_bounds__(256) void kCA(const float* __restrict__ key,
                                           const float* __restrict__ value,
                                           const float* __restrict__ step_size,
                                           float* __restrict__ rp,
                                           const float* __restrict__ LQ,
                                           const float* __restrict__ l2,
                                           float* __restrict__ KR,
                                           float* __restrict__ r2) {
    int blk = blockIdx.x; int bh = blk >> 5; int k = blk & 31;
    int h = bh % NH_; int t = threadIdx.x;
    __shared__ __align__(16) char pool[55296];
    short (*Ah)[72] = (short(*)[72])(pool);
    short (*Am)[72] = (short(*)[72])(pool + 9216);
    short (*Al)[72] = (short(*)[72])(pool + 18432);
    short (*Bh)[72] = (short(*)[72])(pool + 27648);
    short (*Bm)[72] = (short(*)[72])(pool + 36864);
    short (*Bl)[72] = (short(*)[72])(pool + 46080);
    float (*t2S)[66] = (float(*)[66])(pool);   // 16896 B, aliases Ah+part of Am

    float sp1 = softplus_f(step_size[h * 8 + 4 + STEP]);
    float* rpk = rp + ((size_t)(bh * 32 + k)) * 4096;

    // ---- owner inputs issued early ----
    int jo = t >> 2, c0 = (t & 3) * 16;
    float rv[16];
    if (STEP == 0) {
        #pragma unroll
        for (int i = 0; i < 16; ++i) rv[i] = 0.125f;
    } else {
        #pragma unroll
        for (int q4 = 0; q4 < 4; ++q4) {
            float4 v = *(const float4*)&rpk[jo * 64 + c0 + q4 * 4];
            rv[q4*4] = v.x; rv[q4*4+1] = v.y; rv[q4*4+2] = v.z; rv[q4*4+3] = v.w;
        }
    }
    float l2j = l2[(bh * 32 + k) * 64 + jo];

    // ---- staging: LQ -> A planes, K -> B planes ----
    #pragma unroll
    for (int it = 0; it < 4; ++it) {
        int idx = t + 256 * it;
        int r = idx >> 4, c4 = (idx & 15) * 4;
        float4 a = *(const float4*)&LQ[((size_t)(bh * 64 + r) * 32 + k) * 64 + c4];
        float4 b = *(const float4*)&key[((size_t)bh * SS_ + k * 64 + r) * 64 + c4];
        u16 h0, m0_, l0_, h1, m1, l1, h2, m2, l2_, h3, m3, l3;
        split3(a.x, h0, m0_, l0_); split3(a.y, h1, m1, l1);
        split3(a.z, h2, m2, l2_); split3(a.w, h3, m3, l3);
        *(short4*)&Ah[r][c4] = make_short4(h0, h1, h2, h3);
        *(short4*)&Am[r][c4] = make_short4(m0_, m1, m2, m3);
        *(short4*)&Al[r][c4] = make_short4(l0_, l1, l2_, l3);
        split3(b.x, h0, m0_, l0_); split3(b.y, h1, m1, l1);
        split3(b.z, h2, m2, l2_); split3(b.w, h3, m3, l3);
        *(short4*)&Bh[r][c4] = make_short4(h0, h1, h2, h3);
        *(short4*)&Bm[r][c4] = make_short4(m0_, m1, m2, m3);
        *(short4*)&Bl[r][c4] = make_short4(l0_, l1, l2_, l3);
    }
    float s2 = 0.f;
    #pragma unroll
    for (int i = 0; i < 16; ++i) s2 += rv[i] * rv[i];
    s2 += __shfl_xor(s2, 1); s2 += __shfl_xor(s2, 2);
    float nrm = sqrtf(s2);
    float invn = (nrm > 0.f) ? 1.0f / nrm : 0.f;
    __syncthreads();   // sync1

    int w = t >> 6, lane = t & 63;
    int fr = lane & 15, fk = (lane >> 4) * 8;
    int m0 = w * 16;

    // ---- t2r[j][i] = LQ . K^T  (C 64x64; wave w owns 16-row slab, 4 n-tiles) ----
    f4v acc0 = {0,0,0,0}, acc1 = {0,0,0,0}, acc2 = {0,0,0,0}, acc3 = {0,0,0,0};
    #pragma unroll
    for (int k0 = 0; k0 < 64; k0 += 32) {
        s8v ah = *(const s8v*)&Ah[m0 + fr][k0 + fk];
        s8v am = *(const s8v*)&Am[m0 + fr][k0 + fk];
        s8v al = *(const s8v*)&Al[m0 + fr][k0 + fk];
        {
            s8v bh_ = *(const s8v*)&Bh[0 + fr][k0 + fk];
            s8v bm_ = *(const s8v*)&Bm[0 + fr][k0 + fk];
            s8v bl_ = *(const s8v*)&Bl[0 + fr][k0 + fk];
            acc0 = mm6(ah, am, al, bh_, bm_, bl_, acc0);
        }
        {
            s8v bh_ = *(const s8v*)&Bh[16 + fr][k0 + fk];
            s8v bm_ = *(const s8v*)&Bm[16 + fr][k0 + fk];
            s8v bl_ = *(const s8v*)&Bl[16 + fr][k0 + fk];
            acc1 = mm6(ah, am, al, bh_, bm_, bl_, acc1);
        }
        {
            s8v bh_ = *(const s8v*)&Bh[32 + fr][k0 + fk];
            s8v bm_ = *(const s8v*)&Bm[32 + fr][k0 + fk];
            s8v bl_ = *(const s8v*)&Bl[32 + fr][k0 + fk];
            acc2 = mm6(ah, am, al, bh_, bm_, bl_, acc2);
        }
        {
            s8v bh_ = *(const s8v*)&Bh[48 + fr][k0 + fk];
            s8v bm_ = *(const s8v*)&Bm[48 + fr][k0 + fk];
            s8v bl_ = *(const s8v*)&Bl[48 + fr][k0 + fk];
            acc3 = mm6(ah, am, al, bh_, bm_, bl_, acc3);
        }
    }
    __syncthreads();   // sync2: all frag reads done; safe to overwrite A region with t2S
    #pragma unroll
    for (int g = 0; g < 4; ++g) {
        int rr = m0 + (lane >> 4) * 4 + g;
        t2S[rr][0  + fr] = acc0[g];
        t2S[rr][16 + fr] = acc1[g];
        t2S[rr][32 + fr] = acc2[g];
        t2S[rr][48 + fr] = acc3[g];
    }
    __syncthreads();   // sync3: t2S complete

    // ---- owner: dr, project, update rp, norms (row jo, 4 lanes x 16 cols) ----
    float dv[16];
    #pragma unroll
    for (int q = 0; q < 16; ++q) dv[q] = t2S[jo][c0 + q];
    float dot = 0.f;
    #pragma unroll
    for (int i = 0; i < 16; ++i) {
        float rs = rv[i] * invn;
        dv[i] = 2.f * rs * (l2j * rs * rs - dv[i]);
        dot += rs * dv[i];
    }
    dot += __shfl_xor(dot, 1); dot += __shfl_xor(dot, 2);
    float s2n = 0.f, s4n = 0.f;
    #pragma unroll
    for (int i = 0; i < 16; ++i) {
        float rs = rv[i] * invn;
        float dd = (dv[i] - rs * dot) * invn;
        rv[i] -= sp1 * dd;
        float x2 = rv[i] * rv[i];
        s2n += x2; s4n += x2 * x2;
    }
    s2n += __shfl_xor(s2n, 1); s2n += __shfl_xor(s2n, 2);
    s4n += __shfl_xor(s4n, 1); s4n += __shfl_xor(s4n, 2);
    float nn = sqrtf(s2n);
    float inn = (nn > 0.f) ? 1.0f / nn : 0.f;
    if (STEP < 3) {
        #pragma unroll
        for (int q4 = 0; q4 < 4; ++q4)
            *(float4*)&rpk[jo * 64 + c0 + q4 * 4] =
                make_float4(rv[q4*4], rv[q4*4+1], rv[q4*4+2], rv[q4*4+3]);
        if ((t & 3) == 0) {
            float i2 = inn * inn;
            r2[(bh * 64 + jo) * 32 + k] = i2 * i2 * s4n;
        }
    }
    __syncthreads();   // sync4: all t2S reads done; A/B regions reusable

    // ---- right' -> A planes (row jo, cols c0..c0+15) ----
    #pragma unroll
    for (int q4 = 0; q4 < 4; ++q4) {
        u16 hh[4], mmx[4], llx[4];
        #pragma unroll
        for (int d = 0; d < 4; ++d) {
            float rs = rv[q4*4 + d] * inn;
            split3(rs * rs, hh[d], mmx[d], llx[d]);
        }
        *(short4*)&Ah[jo][c0 + q4 * 4] = make_short4(hh[0], hh[1], hh[2], hh[3]);
        *(short4*)&Am[jo][c0 + q4 * 4] = make_short4(mmx[0], mmx[1], mmx[2], mmx[3]);
        *(short4*)&Al[jo][c0 + q4 * 4] = make_short4(llx[0], llx[1], llx[2], llx[3]);
    }
    // ---- K^T (or X^T at STEP==3) -> B planes, via 4x4 register blocks ----
    {
        int i0 = (t & 15) * 4, v0 = (t >> 4) * 4;
        const float* src = (STEP == 3) ? value : key;
        float4 xr[4];
        #pragma unroll
        for (int r = 0; r < 4; ++r)
            xr[r] = *(const float4*)&src[((size_t)bh * SS_ + k * 64 + i0 + r) * 64 + v0];
        #pragma unroll
        for (int q = 0; q < 4; ++q) {
            u16 hh[4], mmx[4], llx[4];
            #pragma unroll
            for (int r = 0; r < 4; ++r) split3(fget(xr[r], q), hh[r], mmx[r], llx[r]);
            *(short4*)&Bh[v0 + q][i0] = make_short4(hh[0], hh[1], hh[2], hh[3]);
            *(short4*)&Bm[v0 + q][i0] = make_short4(mmx[0], mmx[1], mmx[2], mmx[3]);
            *(short4*)&Bl[v0 + q][i0] = make_short4(llx[0], llx[1], llx[2], llx[3]);
        }
    }
    __syncthreads();   // sync5

    // ---- KR[j][v] = right' . (K^T)^T  (C 64x64; Y at STEP==3) ----
    {
        f4v oc0 = {0,0,0,0}, oc1 = {0,0,0,0}, oc2 = {0,0,0,0}, oc3 = {0,0,0,0};
        #pragma unroll
        for (int k0 = 0; k0 < 64; k0 += 32) {
            s8v ah = *(const s8v*)&Ah[m0 + fr][k0 + fk];
            s8v am = *(const s8v*)&Am[m0 + fr][k0 + fk];
            s8v al = *(const s8v*)&Al[m0 + fr][k0 + fk];
            {
                s8v bh_ = *(const s8v*)&Bh[0 + fr][k0 + fk];
                s8v bm_ = *(const s8v*)&Bm[0 + fr][k0 + fk];
                s8v bl_ = *(const s8v*)&Bl[0 + fr][k0 + fk];
                oc0 = mm6(ah, am, al, bh_, bm_, bl_, oc0);
            }
            {
                s8v bh_ = *(const s8v*)&Bh[16 + fr][k0 + fk];
                s8v bm_ = *(const s8v*)&Bm[16 + fr][k0 + fk];
                s8v bl_ = *(const s8v*)&Bl[16 + fr][k0 + fk];
                oc1 = mm6(ah, am, al, bh_, bm_, bl_, oc1);
            }
            {
                s8v bh_ = *(const s8v*)&Bh[32 + fr][k0 + fk];
                s8v bm_ = *(const s8v*)&Bm[32 + fr][k0 + fk];
                s8v bl_ = *(const s8v*)&Bl[32 + fr][k0 + fk];
                oc2 = mm6(ah, am, al, bh_, bm_, bl_, oc2);
            }
            {
                s8v bh_ = *(const s8v*)&Bh[48 + fr][k0 + fk];
                s8v bm_ = *(const s8v*)&Bm[48 + fr][k0 + fk];
                s8v bl_ = *(const s8v*)&Bl[48 + fr][k0 + fk];
                oc3 = mm6(ah, am, al, bh_, bm_, bl_, oc3);
            }
        }
        float* KRk = KR + ((size_t)(bh * 32 + k)) * 4096;
        #pragma unroll
        for (int g = 0; g < 4; ++g) {
            int rr = m0 + (lane >> 4) * 4 + g;
            KRk[rr * 64 + 0  + fr] = oc0[g];
            KRk[rr * 64 + 16 + fr] = oc1[g];
            KRk[rr * 64 + 32 + fr] = oc2[g];
            KRk[rr * 64 + 48 + fr] = oc3[g];
        }
    }
}

// kZ: one block (4 waves) per (bh,j).  Z = left . Y on MFMA.
__global__ __launch_bounds__(256) void kZ(const float* __restrict__ lp,
                                          const float* Y,
                                          float* out) {
    int blk = blockIdx.x; int bh = blk >> 6; int j = blk & 63;
    int t = threadIdx.x;
    __shared__ __align__(16) short YTh[64][40], YTm[64][40], YTl[64][40];  // Y^T [v][k]
    __shared__ __align__(16) short Lh[32][40], Lm[32][40], Ll[32][40];     // le [l][k]

    if (t < 128) {
        int k0 = 4 * (t >> 4), v0 = 4 * (t & 15);
        float4 x[4];
        #pragma unroll
        for (int r = 0; r < 4; ++r)
            x[r] = *(const float4*)&Y[((size_t)(bh * 32 + k0 + r) * 64 + j) * 64 + v0];
        #pragma unroll
        for (int q = 0; q < 4; ++q) {
            u16 hh[4], mm[4], ll[4];
            #pragma unroll
            for (int r = 0; r < 4; ++r) split3(fget(x[r], q), hh[r], mm[r], ll[r]);
            *(short4*)&YTh[v0 + q][k0] = make_short4(hh[0], hh[1], hh[2], hh[3]);
            *(short4*)&YTm[v0 + q][k0] = make_short4(mm[0], mm[1], mm[2], mm[3]);
            *(short4*)&YTl[v0 + q][k0] = make_short4(ll[0], ll[1], ll[2], ll[3]);
        }
    }
    // normalize lp -> le planes
    int lo = t >> 3, c0 = (t & 7) * 4;
    const float* lpj = lp + ((size_t)(bh * 64 + j)) * 1024;
    float4 v = *(const float4*)&lpj[lo * 32 + c0];
    float s = v.x*v.x + v.y*v.y + v.z*v.z + v.w*v.w;
    s += __shfl_xor(s, 1); s += __shfl_xor(s, 2); s += __shfl_xor(s, 4);
    float n = sqrtf(s);
    float invn = (n > 0.f) ? 1.0f / n : 0.f;
    {
        float le[4] = {v.x * invn, v.y * invn, v.z * invn, v.w * invn};
        u16 hh[4], mm[4], ll[4];
        #pragma unroll
        for (int d = 0; d < 4; ++d) split3(le[d] * le[d], hh[d], mm[d], ll[d]);
        *(short4*)&Lh[lo][c0] = make_short4(hh[0], hh[1], hh[2], hh[3]);
        *(short4*)&Lm[lo][c0] = make_short4(mm[0], mm[1], mm[2], mm[3]);
        *(short4*)&Ll[lo][c0] = make_short4(ll[0], ll[1], ll[2], ll[3]);
    }
    __syncthreads();

    int w = t >> 6, lane = t & 63;
    int fr = lane & 15, fk = (lane >> 4) * 8;
    int m0 = (w & 1) * 16, nb = (w >> 1) * 32;
    s8v ah = *(const s8v*)&Lh[m0 + fr][fk];
    s8v am = *(const s8v*)&Lm[m0 + fr][fk];
    s8v al = *(const s8v*)&Ll[m0 + fr][fk];
    #pragma unroll
    for (int half = 0; half < 2; ++half) {
        int n0 = nb + half * 16;
        s8v bh_ = *(const s8v*)&YTh[n0 + fr][fk];
        s8v bm_ = *(const s8v*)&YTm[n0 + fr][fk];
        s8v bl_ = *(const s8v*)&YTl[n0 + fr][fk];
        f4v acc = {0, 0, 0, 0};
        acc = mm6(ah, am, al, bh_, bm_, bl_, acc);
        #pragma unroll
        for (int g = 0; g < 4; ++g)
            out[((size_t)bh * SS_ + (m0 + (lane >> 4) * 4 + g) * 64 + j) * 64 + n0 + fr] = acc[g];
    }
}

extern "C" void kernel_launch(void* const* d_in, const int* in_sizes, int n_in,
                              void* d_out, int out_size, void* d_ws, size_t ws_size,
                              hipStream_t stream) {
    const float* query = (const float*)d_in[0];
    const float* key   = (const float*)d_in[1];
    const float* value = (const float*)d_in[2];
    const float* attn  = (const float*)d_in[3];
    const float* ss    = (const float*)d_in[4];
    float* out = (float*)d_out;

    const size_t n_lp = (size_t)BH_ * 64 * 32 * 32;
    const size_t n_rp = (size_t)BH_ * 32 * 64 * 64;
    const size_t n_LQ = (size_t)BH_ * 64 * 32 * 64;
    const size_t n_r2 = (size_t)BH_ * 64 * 32;
    const size_t n_l2 = (size_t)BH_ * 32 * 64;
    const size_t need = (n_lp + n_rp + n_LQ + n_r2 + n_l2) * sizeof(float); // ~63.7 MB
    if (ws_size < need) return;

    float* ws = (float*)d_ws;
    float* lp = ws;
    float* rp = lp + n_lp;
    float* LQ = rp + n_rp;
    float* r2 = LQ + n_LQ;
    float* l2 = r2 + n_r2;
    float* KR = out;       // KR / Y aliased onto d_out
    float* mean = r2;      // K-block means live in r2 until kCA<0> writes real r2

    const int gK = BH_ * 32;   // 1536
    const int gJ = BH_ * 64;   // 3072

    kA0<<<gK, dim3(64), 0, stream>>>(key, mean);
    kB<0><<<gJ, dim3(256), 0, stream>>>(query, attn, ss, lp, mean, r2, LQ, l2);
    kCA<0><<<gK, dim3(256), 0, stream>>>(key, value, ss, rp, LQ, l2, KR, r2);
    kB<1><<<gJ, dim3(256), 0, stream>>>(query, attn, ss, lp, KR, r2, LQ, l2);
    kCA<1><<<gK, dim3(256), 0, stream>>>(key, value, ss, rp, LQ, l2, KR, r2);
    kB<2><<<gJ, dim3(256), 0, stream>>>(query, attn, ss, lp, KR, r2, LQ, l2);
    kCA<2><<<gK, dim3(256), 0, stream>>>(key, value, ss, rp, LQ, l2, KR, r2);
    kB<3><<<gJ, dim3(256), 0, stream>>>(query, attn, ss, lp, KR, r2, LQ, l2);
    kCA<3><<<gK, dim3(256), 0, stream>>>(key, value, ss, rp, LQ, l2, KR, r2);  // emits Y
    kZ<<<gJ, dim3(256), 0, stream>>>(lp, KR, out);
}